// Round 1
// baseline (8773.174 us; speedup 1.0000x reference)
//
#include <hip/hip_runtime.h>
#include <math.h>

#define T_ 512
#define N_ 64
#define E_ 1024
#define H_ 320
#define J_ 512
#define V_ 29
#define BLANK_ 28
#define MAXSYM_ 30
#define RESW_ (MAXSYM_ * T_)   // 15360

// ============================================================
// Kernel 1: Fproj[(t*N+n), j] = f[t,n,:] @ w_f[j,:] + b_j[j]
// M=32768, J=512, K=1024, fp32 (no fp32 MFMA on CDNA4).
// 128x128 tile, 256 threads, 8x8 per thread, BK=8.
// ============================================================
#define BM_ 128
#define BN_ 128
#define BK_ 8

__global__ __launch_bounds__(256) void fproj_gemm(
    const float* __restrict__ A,   // (32768, 1024) = f
    const float* __restrict__ B,   // (512, 1024)   = w_f
    const float* __restrict__ bj,  // (512,)
    float* __restrict__ C) {       // (32768, 512)
  __shared__ __align__(16) float As[BK_][BM_ + 4];
  __shared__ __align__(16) float Bs[BK_][BN_ + 4];
  const int tid = threadIdx.x;
  const int m0 = blockIdx.x * BM_;
  const int j0 = blockIdx.y * BN_;
  const int tx = tid & 15, ty = tid >> 4;
  const int sm = tid >> 1;
  const int sk = (tid & 1) << 2;

  float acc[8][8];
#pragma unroll
  for (int i = 0; i < 8; ++i)
#pragma unroll
    for (int j = 0; j < 8; ++j) acc[i][j] = 0.f;

  for (int kc = 0; kc < E_; kc += BK_) {
    float4 av = *(const float4*)(A + (size_t)(m0 + sm) * E_ + kc + sk);
    float4 bv = *(const float4*)(B + (size_t)(j0 + sm) * E_ + kc + sk);
    __syncthreads();
    As[sk + 0][sm] = av.x; As[sk + 1][sm] = av.y;
    As[sk + 2][sm] = av.z; As[sk + 3][sm] = av.w;
    Bs[sk + 0][sm] = bv.x; Bs[sk + 1][sm] = bv.y;
    Bs[sk + 2][sm] = bv.z; Bs[sk + 3][sm] = bv.w;
    __syncthreads();
#pragma unroll
    for (int k = 0; k < BK_; ++k) {
      float a_[8], b_[8];
      *(float4*)&a_[0] = *(const float4*)&As[k][ty * 8];
      *(float4*)&a_[4] = *(const float4*)&As[k][ty * 8 + 4];
      *(float4*)&b_[0] = *(const float4*)&Bs[k][tx * 8];
      *(float4*)&b_[4] = *(const float4*)&Bs[k][tx * 8 + 4];
#pragma unroll
      for (int i = 0; i < 8; ++i)
#pragma unroll
        for (int j = 0; j < 8; ++j) acc[i][j] += a_[i] * b_[j];
    }
  }

#pragma unroll
  for (int i = 0; i < 8; ++i) {
    const size_t m = (size_t)(m0 + ty * 8 + i);
#pragma unroll
    for (int j = 0; j < 8; j += 4) {
      float4 v;
      v.x = acc[i][j + 0] + bj[j0 + tx * 8 + j + 0];
      v.y = acc[i][j + 1] + bj[j0 + tx * 8 + j + 1];
      v.z = acc[i][j + 2] + bj[j0 + tx * 8 + j + 2];
      v.w = acc[i][j + 3] + bj[j0 + tx * 8 + j + 3];
      *(float4*)(C + m * J_ + j0 + tx * 8 + j) = v;
    }
  }
}

// ============================================================
// Kernel 2: per-row greedy decode. 1 block per row, 512 threads.
// ============================================================
__device__ __forceinline__ float sigmoidf_(float x) {
  return 1.f / (1.f + expf(-x));
}

// Recompute pending LSTM state (in place) + gproj = h1_new @ w_g^T.
// Called by ALL 512 threads; h/c arrays hold committed state on entry,
// pending state on exit (pending == committed-at-next-emit semantics).
__device__ __forceinline__ void lstm_and_gproj(
    int last, int tid,
    const float* __restrict__ emb,
    const float* __restrict__ wi0, const float* __restrict__ wh0,
    const float* __restrict__ bi0, const float* __restrict__ bh0,
    const float* __restrict__ wi1, const float* __restrict__ wh1,
    const float* __restrict__ bi1, const float* __restrict__ bh1,
    const float* __restrict__ w_g,
    float* x_in, float* h0s, float* c0s, float* h1s, float* c1s,
    float* gates, float* gproj) {
  // embedding input (zeros for last < 0)
  if (tid < H_) x_in[tid] = (last < 0) ? 0.f : emb[(size_t)last * H_ + tid];
  __syncthreads();

  // ---- layer 0 gates ----
  for (int o = tid; o < 4 * H_; o += 512) {
    const float* wir = wi0 + (size_t)o * H_;
    const float* whr = wh0 + (size_t)o * H_;
    float acc = bi0[o] + bh0[o];
    for (int k = 0; k < H_; k += 4) {
      float4 xv = *(const float4*)&x_in[k];
      float4 wv = *(const float4*)&wir[k];
      acc += xv.x * wv.x + xv.y * wv.y + xv.z * wv.z + xv.w * wv.w;
    }
    for (int k = 0; k < H_; k += 4) {
      float4 hv = *(const float4*)&h0s[k];
      float4 wv = *(const float4*)&whr[k];
      acc += hv.x * wv.x + hv.y * wv.y + hv.z * wv.z + hv.w * wv.w;
    }
    gates[o] = acc;
  }
  __syncthreads();
  if (tid < H_) {
    float ig = sigmoidf_(gates[tid]);
    float fg = sigmoidf_(gates[H_ + tid]);
    float gg = tanhf(gates[2 * H_ + tid]);
    float og = sigmoidf_(gates[3 * H_ + tid]);
    float c2 = fg * c0s[tid] + ig * gg;
    c0s[tid] = c2;
    h0s[tid] = og * tanhf(c2);
  }
  __syncthreads();

  // ---- layer 1 gates (x = new h0) ----
  for (int o = tid; o < 4 * H_; o += 512) {
    const float* wir = wi1 + (size_t)o * H_;
    const float* whr = wh1 + (size_t)o * H_;
    float acc = bi1[o] + bh1[o];
    for (int k = 0; k < H_; k += 4) {
      float4 xv = *(const float4*)&h0s[k];
      float4 wv = *(const float4*)&wir[k];
      acc += xv.x * wv.x + xv.y * wv.y + xv.z * wv.z + xv.w * wv.w;
    }
    for (int k = 0; k < H_; k += 4) {
      float4 hv = *(const float4*)&h1s[k];
      float4 wv = *(const float4*)&whr[k];
      acc += hv.x * wv.x + hv.y * wv.y + hv.z * wv.z + hv.w * wv.w;
    }
    gates[o] = acc;
  }
  __syncthreads();
  if (tid < H_) {
    float ig = sigmoidf_(gates[tid]);
    float fg = sigmoidf_(gates[H_ + tid]);
    float gg = tanhf(gates[2 * H_ + tid]);
    float og = sigmoidf_(gates[3 * H_ + tid]);
    float c2 = fg * c1s[tid] + ig * gg;
    c1s[tid] = c2;
    h1s[tid] = og * tanhf(c2);
  }
  __syncthreads();

  // ---- gproj[j] = sum_k h1_new[k] * w_g[j,k] ----
  {
    const float* wgr = w_g + (size_t)tid * H_;
    float acc = 0.f;
    for (int k = 0; k < H_; k += 4) {
      float4 hv = *(const float4*)&h1s[k];
      float4 wv = *(const float4*)&wgr[k];
      acc += hv.x * wv.x + hv.y * wv.y + hv.z * wv.z + hv.w * wv.w;
    }
    gproj[tid] = acc;
  }
  __syncthreads();
}

__global__ __launch_bounds__(512) void decode_kernel(
    const float* __restrict__ Fproj,   // (T*N, J) includes b_j
    const int* __restrict__ f_lens,
    const float* __restrict__ emb,
    const float* __restrict__ wi0, const float* __restrict__ wh0,
    const float* __restrict__ bi0, const float* __restrict__ bh0,
    const float* __restrict__ wi1, const float* __restrict__ wh1,
    const float* __restrict__ bi1, const float* __restrict__ bh1,
    const float* __restrict__ w_g,
    const float* __restrict__ w_o,     // (29, 512)
    const float* __restrict__ b_o,     // (29,)
    int* __restrict__ res,             // (64, 15360)
    int* __restrict__ nsym) {          // (64,)
  const int row = blockIdx.x;
  const int tid = threadIdx.x;
  const int f_len = f_lens[row];

  __shared__ __align__(16) float x_in[H_];
  __shared__ __align__(16) float h0s[H_], c0s[H_], h1s[H_], c1s[H_];
  __shared__ __align__(16) float gates[4 * H_];
  __shared__ __align__(16) float gproj[J_];
  __shared__ __align__(16) float hjs[J_];
  __shared__ float logits[32];
  __shared__ int st[8];  // 0:t  1:sym_add  2:res_idx  3:last  4:emit

  // init this row's result slots to -1
  for (int i = tid; i < RESW_; i += 512) res[(size_t)row * RESW_ + i] = -1;

  // w_o held in registers: thread (grp, ti) owns w_o[grp][ti + 16k]
  const int grp = tid >> 4;
  const int ti = tid & 15;
  float wo_reg[32];
  float bo_reg = 0.f;
  if (grp < V_) {
#pragma unroll
    for (int k = 0; k < 32; ++k) wo_reg[k] = w_o[(size_t)grp * J_ + ti + 16 * k];
    bo_reg = b_o[grp];
  }

  if (tid < H_) { h0s[tid] = 0.f; c0s[tid] = 0.f; h1s[tid] = 0.f; c1s[tid] = 0.f; }
  if (tid == 0) { st[0] = 0; st[1] = 0; st[2] = -1; st[3] = -1; st[4] = 0; }
  __syncthreads();

  // initial pending LSTM state from (last=-1, h=0, c=0)
  lstm_and_gproj(-1, tid, emb, wi0, wh0, bi0, bh0, wi1, wh1, bi1, bh1, w_g,
                 x_in, h0s, c0s, h1s, c1s, gates, gproj);

  int t_loc = 0;
  float fp_cur = Fproj[(size_t)row * J_ + tid];  // t = 0 row

  while (t_loc < f_len) {
    // prefetch next time row (t advances by <= 1 per step)
    const int tnext = (t_loc + 1 < T_) ? t_loc + 1 : T_ - 1;
    float fp_next = Fproj[((size_t)tnext * N_ + row) * J_ + tid];

    // hj = relu(Fproj[t] + gproj)
    float hj = fp_cur + gproj[tid];
    hjs[tid] = hj > 0.f ? hj : 0.f;
    __syncthreads();

    // logits[grp] = sum_j hjs[j] * w_o[grp][j] + b_o[grp]
    float p = 0.f;
    if (grp < V_) {
#pragma unroll
      for (int k = 0; k < 32; ++k) p += hjs[ti + 16 * k] * wo_reg[k];
    }
#pragma unroll
    for (int s = 8; s; s >>= 1) p += __shfl_xor(p, s, 16);
    if (grp < V_ && ti == 0) logits[grp] = p + bo_reg;
    __syncthreads();

    if (tid == 0) {
      float best = logits[0];
      int bi = 0;
      for (int v = 1; v < V_; ++v) {
        float lv = logits[v];
        if (lv > best) { best = lv; bi = v; }
      }
      int sym_add = st[1], res_idx = st[2];
      int emit = (bi != BLANK_) && (sym_add < MAXSYM_);
      if (emit) {
        res_idx += 1;
        res[(size_t)row * RESW_ + res_idx] = bi;
        st[1] = sym_add + 1;
        st[2] = res_idx;
        st[3] = bi;
      } else {
        st[0] = st[0] + 1;
        st[1] = 0;
      }
      st[4] = emit;
    }
    __syncthreads();

    const int emit = st[4];
    const int t_new = st[0];
    if (t_new != t_loc) { fp_cur = fp_next; t_loc = t_new; }

    if (emit) {
      // state advanced: recompute pending LSTM + gproj with new last symbol
      lstm_and_gproj(st[3], tid, emb, wi0, wh0, bi0, bh0, wi1, wh1, bi1, bh1,
                     w_g, x_in, h0s, c0s, h1s, c1s, gates, gproj);
    }
  }

  if (tid == 0) nsym[row] = st[2] + 1;
}

// ============================================================
extern "C" void kernel_launch(void* const* d_in, const int* in_sizes, int n_in,
                              void* d_out, int out_size, void* d_ws, size_t ws_size,
                              hipStream_t stream) {
  const float* f      = (const float*)d_in[0];
  const int*   f_lens = (const int*)d_in[1];
  const float* emb    = (const float*)d_in[2];
  const float* wi0    = (const float*)d_in[3];
  const float* wh0    = (const float*)d_in[4];
  const float* bi0    = (const float*)d_in[5];
  const float* bh0    = (const float*)d_in[6];
  const float* wi1    = (const float*)d_in[7];
  const float* wh1    = (const float*)d_in[8];
  const float* bi1    = (const float*)d_in[9];
  const float* bh1    = (const float*)d_in[10];
  const float* w_f    = (const float*)d_in[11];
  const float* w_g    = (const float*)d_in[12];
  const float* b_j    = (const float*)d_in[13];
  const float* w_o    = (const float*)d_in[14];
  const float* b_o    = (const float*)d_in[15];

  int* out  = (int*)d_out;
  int* res  = out;                    // (64, 15360)
  int* nsym = out + (size_t)N_ * RESW_;  // (64,)

  float* Fproj = (float*)d_ws;  // needs T*N*J*4 = 64 MiB of workspace

  dim3 ggrid(T_ * N_ / BM_, J_ / BN_);  // (256, 4)
  fproj_gemm<<<ggrid, 256, 0, stream>>>(f, w_f, b_j, Fproj);

  decode_kernel<<<N_, 512, 0, stream>>>(Fproj, f_lens, emb, wi0, wh0, bi0, bh0,
                                        wi1, wh1, bi1, bh1, w_g, w_o, b_o,
                                        res, nsym);
}

// Round 2
// 2358.205 us; speedup vs baseline: 3.7203x; 3.7203x over previous
//
#include <hip/hip_runtime.h>
#include <math.h>

#define T_ 512
#define N_ 64
#define E_ 1024
#define H_ 320
#define HS_ 80            // H_/4 per-block h-slice
#define J_ 512
#define GS_ 128           // J_/4 per-block gproj slice
#define V_ 29
#define BLANK_ 28
#define MAXSYM_ 30
#define RESW_ (MAXSYM_ * T_)   // 15360

// ---------------- static device memory (avoids ws pressure) ----------------
__device__ float g_Xi0[V_][4 * H_];   // Xi0[s][o] = wi0[o,:]@emb[s] + bi0[o] + bh0[o]; row 28 = bias only (last<0)
__device__ float g_b1s[4 * H_];       // bi1 + bh1
__device__ float g_h0x[2][N_][H_];    // exchange buffers, double-buffered by emit parity
__device__ float g_c0x[2][N_][H_];
__device__ float g_h1x[2][N_][H_];
__device__ float g_c1x[2][N_][H_];
__device__ float g_gpx[2][N_][J_];
__device__ unsigned int g_flag[N_];   // monotonic per-row sync counter

// ============================================================
// Kernel 1: Fproj[(t*N+n), j] = f[t,n,:] @ w_f[j,:] + b_j[j]
// ============================================================
#define BM_ 128
#define BN_ 128
#define BK_ 8

__global__ __launch_bounds__(256) void fproj_gemm(
    const float* __restrict__ A, const float* __restrict__ B,
    const float* __restrict__ bj, float* __restrict__ C) {
  __shared__ __align__(16) float As[BK_][BM_ + 4];
  __shared__ __align__(16) float Bs[BK_][BN_ + 4];
  const int tid = threadIdx.x;
  const int m0 = blockIdx.x * BM_;
  const int j0 = blockIdx.y * BN_;
  const int tx = tid & 15, ty = tid >> 4;
  const int sm = tid >> 1;
  const int sk = (tid & 1) << 2;

  float acc[8][8];
#pragma unroll
  for (int i = 0; i < 8; ++i)
#pragma unroll
    for (int j = 0; j < 8; ++j) acc[i][j] = 0.f;

  for (int kc = 0; kc < E_; kc += BK_) {
    float4 av = *(const float4*)(A + (size_t)(m0 + sm) * E_ + kc + sk);
    float4 bv = *(const float4*)(B + (size_t)(j0 + sm) * E_ + kc + sk);
    __syncthreads();
    As[sk + 0][sm] = av.x; As[sk + 1][sm] = av.y;
    As[sk + 2][sm] = av.z; As[sk + 3][sm] = av.w;
    Bs[sk + 0][sm] = bv.x; Bs[sk + 1][sm] = bv.y;
    Bs[sk + 2][sm] = bv.z; Bs[sk + 3][sm] = bv.w;
    __syncthreads();
#pragma unroll
    for (int k = 0; k < BK_; ++k) {
      float a_[8], b_[8];
      *(float4*)&a_[0] = *(const float4*)&As[k][ty * 8];
      *(float4*)&a_[4] = *(const float4*)&As[k][ty * 8 + 4];
      *(float4*)&b_[0] = *(const float4*)&Bs[k][tx * 8];
      *(float4*)&b_[4] = *(const float4*)&Bs[k][tx * 8 + 4];
#pragma unroll
      for (int i = 0; i < 8; ++i)
#pragma unroll
        for (int j = 0; j < 8; ++j) acc[i][j] += a_[i] * b_[j];
    }
  }

#pragma unroll
  for (int i = 0; i < 8; ++i) {
    const size_t m = (size_t)(m0 + ty * 8 + i);
#pragma unroll
    for (int j = 0; j < 8; j += 4) {
      float4 v;
      v.x = acc[i][j + 0] + bj[j0 + tx * 8 + j + 0];
      v.y = acc[i][j + 1] + bj[j0 + tx * 8 + j + 1];
      v.z = acc[i][j + 2] + bj[j0 + tx * 8 + j + 2];
      v.w = acc[i][j + 3] + bj[j0 + tx * 8 + j + 3];
      *(float4*)(C + m * J_ + j0 + tx * 8 + j) = v;
    }
  }
}

// ============================================================
// Kernel 2: init (flags + res fill). Must run before decode each call.
// ============================================================
__global__ void init_kernel(int* __restrict__ res) {
  const int idx = blockIdx.x * blockDim.x + threadIdx.x;
  if (idx < N_) g_flag[idx] = 0u;
  const int stride = gridDim.x * blockDim.x;
  for (size_t i = idx; i < (size_t)N_ * RESW_; i += stride) res[i] = -1;
}

// ============================================================
// Kernel 3: Xi0 table (29 x 1280) + b1s. Preserves round-1 summation order:
// acc = (bi0+bh0) + sum_k x[k]*wi0[o,k] sequentially in float4 steps.
// ============================================================
__global__ __launch_bounds__(256) void xi0_kernel(
    const float* __restrict__ emb, const float* __restrict__ wi0,
    const float* __restrict__ bi0, const float* __restrict__ bh0,
    const float* __restrict__ bi1, const float* __restrict__ bh1) {
  __shared__ __align__(16) float xs[H_];
  const int s = blockIdx.x;   // 0..28 (28 = null / last<0)
  const int tid = threadIdx.x;
  for (int i = tid; i < H_; i += 256)
    xs[i] = (s < V_ - 1) ? emb[(size_t)s * H_ + i] : 0.f;
  __syncthreads();
  for (int o = tid; o < 4 * H_; o += 256) {
    float acc = bi0[o] + bh0[o];
    if (s < V_ - 1) {
      const float* wr = wi0 + (size_t)o * H_;
      for (int k = 0; k < H_; k += 4) {
        float4 x4 = *(const float4*)&xs[k];
        float4 w4 = *(const float4*)&wr[k];
        acc += x4.x * w4.x + x4.y * w4.y + x4.z * w4.z + x4.w * w4.w;
      }
    }
    g_Xi0[s][o] = acc;
    if (s == 0) g_b1s[o] = bi1[o] + bh1[o];
  }
}

// ============================================================
// Kernel 4: decode, 4 blocks per row (256 blocks x 512 threads, 1/CU).
// ============================================================
__device__ __forceinline__ float sigmoidf_(float x) {
  return 1.f / (1.f + expf(-x));
}

// One sync round among the 4 blocks of a row: monotonic counter, +4 per round.
__device__ __forceinline__ void flag_round(int row, int tid, int* target) {
  *target += 4;
  __syncthreads();  // drains vmcnt: all exchange stores complete before flag
  if (tid == 0) {
    __hip_atomic_fetch_add(&g_flag[row], 1u, __ATOMIC_RELEASE,
                           __HIP_MEMORY_SCOPE_AGENT);
    while (__hip_atomic_load(&g_flag[row], __ATOMIC_ACQUIRE,
                             __HIP_MEMORY_SCOPE_AGENT) < (unsigned)*target)
      __builtin_amdgcn_s_sleep(2);
  }
  __syncthreads();
}

// Recompute pending LSTM state + gproj from symbol s (28 = null).
// Work split 4 ways by h-index slice; state exchanged via agent-scope ops.
__device__ void recompute4(
    int s, int row, int k, int tid, int par, int* target,
    const float* __restrict__ wh0, const float* __restrict__ wi1,
    const float* __restrict__ wh1, const float* __restrict__ w_g,
    float* h0s, float* c0s, float* h1s, float* c1s,
    float* gates, float* gproj) {
  // ---- layer 0: this block's 4x80 gate rows; input part from Xi0 table ----
  if (tid < 4 * HS_) {
    const int g = tid / HS_;
    const int i = tid - g * HS_;
    const int o = g * H_ + k * HS_ + i;
    const float* wr = wh0 + (size_t)o * H_;
    float acc = g_Xi0[s][o];
    for (int kk = 0; kk < H_; kk += 4) {
      float4 h4 = *(const float4*)&h0s[kk];
      float4 w4 = *(const float4*)&wr[kk];
      acc += h4.x * w4.x + h4.y * w4.y + h4.z * w4.z + h4.w * w4.w;
    }
    gates[tid] = acc;
  }
  __syncthreads();
  if (tid < HS_) {
    const int hi = k * HS_ + tid;
    float ig = sigmoidf_(gates[tid]);
    float fg = sigmoidf_(gates[HS_ + tid]);
    float gg = tanhf(gates[2 * HS_ + tid]);
    float og = sigmoidf_(gates[3 * HS_ + tid]);
    float c2 = fg * c0s[hi] + ig * gg;
    float h2 = og * tanhf(c2);
    __hip_atomic_store(&g_c0x[par][row][hi], c2, __ATOMIC_RELAXED,
                       __HIP_MEMORY_SCOPE_AGENT);
    __hip_atomic_store(&g_h0x[par][row][hi], h2, __ATOMIC_RELAXED,
                       __HIP_MEMORY_SCOPE_AGENT);
  }
  flag_round(row, tid, target);
  if (tid < H_) {
    h0s[tid] = __hip_atomic_load(&g_h0x[par][row][tid], __ATOMIC_RELAXED,
                                 __HIP_MEMORY_SCOPE_AGENT);
    c0s[tid] = __hip_atomic_load(&g_c0x[par][row][tid], __ATOMIC_RELAXED,
                                 __HIP_MEMORY_SCOPE_AGENT);
  }
  __syncthreads();

  // ---- layer 1: gates = b1s + wi1@h0_new + wh1@h1_old ----
  if (tid < 4 * HS_) {
    const int g = tid / HS_;
    const int i = tid - g * HS_;
    const int o = g * H_ + k * HS_ + i;
    const float* wir = wi1 + (size_t)o * H_;
    const float* whr = wh1 + (size_t)o * H_;
    float acc = g_b1s[o];
    for (int kk = 0; kk < H_; kk += 4) {
      float4 x4 = *(const float4*)&h0s[kk];
      float4 w4 = *(const float4*)&wir[kk];
      acc += x4.x * w4.x + x4.y * w4.y + x4.z * w4.z + x4.w * w4.w;
    }
    for (int kk = 0; kk < H_; kk += 4) {
      float4 h4 = *(const float4*)&h1s[kk];
      float4 w4 = *(const float4*)&whr[kk];
      acc += h4.x * w4.x + h4.y * w4.y + h4.z * w4.z + h4.w * w4.w;
    }
    gates[tid] = acc;
  }
  __syncthreads();
  if (tid < HS_) {
    const int hi = k * HS_ + tid;
    float ig = sigmoidf_(gates[tid]);
    float fg = sigmoidf_(gates[HS_ + tid]);
    float gg = tanhf(gates[2 * HS_ + tid]);
    float og = sigmoidf_(gates[3 * HS_ + tid]);
    float c2 = fg * c1s[hi] + ig * gg;
    float h2 = og * tanhf(c2);
    __hip_atomic_store(&g_c1x[par][row][hi], c2, __ATOMIC_RELAXED,
                       __HIP_MEMORY_SCOPE_AGENT);
    __hip_atomic_store(&g_h1x[par][row][hi], h2, __ATOMIC_RELAXED,
                       __HIP_MEMORY_SCOPE_AGENT);
  }
  flag_round(row, tid, target);
  if (tid < H_) {
    h1s[tid] = __hip_atomic_load(&g_h1x[par][row][tid], __ATOMIC_RELAXED,
                                 __HIP_MEMORY_SCOPE_AGENT);
    c1s[tid] = __hip_atomic_load(&g_c1x[par][row][tid], __ATOMIC_RELAXED,
                                 __HIP_MEMORY_SCOPE_AGENT);
  }
  __syncthreads();

  // ---- gproj slice: j in [k*128,(k+1)*128), 4 threads per output ----
  {
    const int j = k * GS_ + (tid >> 2);
    const int q = tid & 3;
    const float* wgr = w_g + (size_t)j * H_;
    float acc = 0.f;
    for (int kk = q * HS_; kk < (q + 1) * HS_; kk += 4) {
      float4 h4 = *(const float4*)&h1s[kk];
      float4 w4 = *(const float4*)&wgr[kk];
      acc += h4.x * w4.x + h4.y * w4.y + h4.z * w4.z + h4.w * w4.w;
    }
    acc += __shfl_xor(acc, 1, 4);
    acc += __shfl_xor(acc, 2, 4);
    if (q == 0)
      __hip_atomic_store(&g_gpx[par][row][j], acc, __ATOMIC_RELAXED,
                         __HIP_MEMORY_SCOPE_AGENT);
  }
  flag_round(row, tid, target);
  gproj[tid] = __hip_atomic_load(&g_gpx[par][row][tid], __ATOMIC_RELAXED,
                                 __HIP_MEMORY_SCOPE_AGENT);
  __syncthreads();
}

__global__ __launch_bounds__(512) void decode4(
    const float* __restrict__ Fproj, const int* __restrict__ f_lens,
    const float* __restrict__ wh0,
    const float* __restrict__ wi1, const float* __restrict__ wh1,
    const float* __restrict__ w_g,
    const float* __restrict__ w_o, const float* __restrict__ b_o,
    int* __restrict__ res, int* __restrict__ nsym) {
  const int bid = blockIdx.x;
  const int row = bid >> 2;
  const int k = bid & 3;
  const int tid = threadIdx.x;
  const int f_len = f_lens[row];

  __shared__ __align__(16) float h0s[H_], c0s[H_], h1s[H_], c1s[H_];
  __shared__ __align__(16) float gates[4 * HS_];
  __shared__ __align__(16) float gproj[J_];
  __shared__ __align__(16) float hjs[J_];
  __shared__ float logits[32];
  __shared__ int st[8];  // 0:t 1:sym_add 2:res_idx 3:last 4:emit

  // w_o in registers: thread (grp, ti) owns w_o[grp][ti + 16k]
  const int grp = tid >> 4;
  const int ti = tid & 15;
  float wo_reg[32];
  float bo_reg = 0.f;
  if (grp < V_) {
#pragma unroll
    for (int kk = 0; kk < 32; ++kk)
      wo_reg[kk] = w_o[(size_t)grp * J_ + ti + 16 * kk];
    bo_reg = b_o[grp];
  }

  if (tid < H_) { h0s[tid] = 0.f; c0s[tid] = 0.f; h1s[tid] = 0.f; c1s[tid] = 0.f; }
  if (tid == 0) { st[0] = 0; st[1] = 0; st[2] = -1; st[3] = -1; st[4] = 0; }
  int target = 0;
  int ecount = 0;
  __syncthreads();

  // initial pending state from (last=-1, h=0, c=0); Xi0 row 28 = zero input
  recompute4(BLANK_, row, k, tid, ecount & 1, &target, wh0, wi1, wh1, w_g,
             h0s, c0s, h1s, c1s, gates, gproj);
  ecount = 1;

  int t_loc = 0;
  float fp_cur = Fproj[(size_t)row * J_ + tid];  // t=0 row

  while (t_loc < f_len) {
    const int tnext = (t_loc + 1 < T_) ? t_loc + 1 : T_ - 1;
    float fp_next = Fproj[((size_t)tnext * N_ + row) * J_ + tid];

    float hj = fp_cur + gproj[tid];
    hjs[tid] = hj > 0.f ? hj : 0.f;
    __syncthreads();

    float p = 0.f;
    if (grp < V_) {
#pragma unroll
      for (int kk = 0; kk < 32; ++kk) p += hjs[ti + 16 * kk] * wo_reg[kk];
    }
#pragma unroll
    for (int sft = 8; sft; sft >>= 1) p += __shfl_xor(p, sft, 16);
    if (grp < V_ && ti == 0) logits[grp] = p + bo_reg;
    __syncthreads();

    if (tid < 32) {
      float lv = (tid < V_) ? logits[tid] : -INFINITY;
      int li = tid;
#pragma unroll
      for (int sft = 16; sft; sft >>= 1) {
        float ov = __shfl_xor(lv, sft, 32);
        int oi = __shfl_xor(li, sft, 32);
        if (ov > lv || (ov == lv && oi < li)) { lv = ov; li = oi; }
      }
      if (tid == 0) {
        int sym_add = st[1], res_idx = st[2];
        int emit = (li != BLANK_) && (sym_add < MAXSYM_);
        if (emit) {
          res_idx += 1;
          if (k == 0) res[(size_t)row * RESW_ + res_idx] = li;
          st[1] = sym_add + 1; st[2] = res_idx; st[3] = li;
        } else {
          st[0] = st[0] + 1; st[1] = 0;
        }
        st[4] = emit;
      }
    }
    __syncthreads();

    const int emit = st[4];
    if (st[0] != t_loc) { fp_cur = fp_next; t_loc = st[0]; }

    if (emit) {
      recompute4(st[3], row, k, tid, ecount & 1, &target, wh0, wi1, wh1, w_g,
                 h0s, c0s, h1s, c1s, gates, gproj);
      ecount++;
    }
  }

  if (k == 0 && tid == 0) nsym[row] = st[2] + 1;
}

// ============================================================
extern "C" void kernel_launch(void* const* d_in, const int* in_sizes, int n_in,
                              void* d_out, int out_size, void* d_ws, size_t ws_size,
                              hipStream_t stream) {
  const float* f      = (const float*)d_in[0];
  const int*   f_lens = (const int*)d_in[1];
  const float* emb    = (const float*)d_in[2];
  const float* wi0    = (const float*)d_in[3];
  const float* wh0    = (const float*)d_in[4];
  const float* bi0    = (const float*)d_in[5];
  const float* bh0    = (const float*)d_in[6];
  const float* wi1    = (const float*)d_in[7];
  const float* wh1    = (const float*)d_in[8];
  const float* bi1    = (const float*)d_in[9];
  const float* bh1    = (const float*)d_in[10];
  const float* w_f    = (const float*)d_in[11];
  const float* w_g    = (const float*)d_in[12];
  const float* b_j    = (const float*)d_in[13];
  const float* w_o    = (const float*)d_in[14];
  const float* b_o    = (const float*)d_in[15];

  int* out  = (int*)d_out;
  int* res  = out;                       // (64, 15360)
  int* nsym = out + (size_t)N_ * RESW_;  // (64,)

  float* Fproj = (float*)d_ws;  // T*N*J*4 = 64 MiB

  init_kernel<<<1024, 256, 0, stream>>>(res);
  xi0_kernel<<<V_, 256, 0, stream>>>(emb, wi0, bi0, bh0, bi1, bh1);

  dim3 ggrid(T_ * N_ / BM_, J_ / BN_);  // (256, 4)
  fproj_gemm<<<ggrid, 256, 0, stream>>>(f, w_f, b_j, Fproj);

  decode4<<<N_ * 4, 512, 0, stream>>>(Fproj, f_lens, wh0, wi1, wh1, w_g,
                                      w_o, b_o, res, nsym);
}

// Round 3
// 2334.381 us; speedup vs baseline: 3.7582x; 1.0102x over previous
//
#include <hip/hip_runtime.h>
#include <math.h>

#define T_ 512
#define N_ 64
#define E_ 1024
#define H_ 320
#define HS_ 80            // H_/4 per-block h-slice
#define J_ 512
#define V_ 29
#define BLANK_ 28
#define MAXSYM_ 30
#define RESW_ (MAXSYM_ * T_)   // 15360

// ---------------- static device memory ----------------
__device__ float g_Xi0[V_][4 * H_];     // wi0@emb[s]+bi0+bh0; row 28 = bias only
__device__ float g_b1s[4 * H_];         // bi1 + bh1
__device__ float g_h0x[2][N_][H_];      // exchange buffers (parity double-buffered)
__device__ float g_h1x[2][N_][H_];
__device__ float g_gpx[2][N_][4][J_];   // gproj partials per source block
__device__ unsigned int g_flag[N_];     // monotonic per-row sync counter

// ============================================================
// Kernel 1: Fproj[(t*N+n), j] = f[t,n,:] @ w_f[j,:] + b_j[j]
// ============================================================
#define BM_ 128
#define BN_ 128
#define BK_ 16

__global__ __launch_bounds__(256) void fproj_gemm(
    const float* __restrict__ A, const float* __restrict__ B,
    const float* __restrict__ bj, float* __restrict__ C) {
  __shared__ __align__(16) float As[BK_][BM_ + 4];
  __shared__ __align__(16) float Bs[BK_][BN_ + 4];
  const int tid = threadIdx.x;
  const int m0 = blockIdx.x * BM_;
  const int j0 = blockIdx.y * BN_;
  const int tx = tid & 15, ty = tid >> 4;
  const int sm = tid >> 1;
  const int sk = (tid & 1) << 3;

  float acc[8][8];
#pragma unroll
  for (int i = 0; i < 8; ++i)
#pragma unroll
    for (int j = 0; j < 8; ++j) acc[i][j] = 0.f;

  for (int kc = 0; kc < E_; kc += BK_) {
    float4 av0 = *(const float4*)(A + (size_t)(m0 + sm) * E_ + kc + sk);
    float4 av1 = *(const float4*)(A + (size_t)(m0 + sm) * E_ + kc + sk + 4);
    float4 bv0 = *(const float4*)(B + (size_t)(j0 + sm) * E_ + kc + sk);
    float4 bv1 = *(const float4*)(B + (size_t)(j0 + sm) * E_ + kc + sk + 4);
    __syncthreads();
    As[sk + 0][sm] = av0.x; As[sk + 1][sm] = av0.y;
    As[sk + 2][sm] = av0.z; As[sk + 3][sm] = av0.w;
    As[sk + 4][sm] = av1.x; As[sk + 5][sm] = av1.y;
    As[sk + 6][sm] = av1.z; As[sk + 7][sm] = av1.w;
    Bs[sk + 0][sm] = bv0.x; Bs[sk + 1][sm] = bv0.y;
    Bs[sk + 2][sm] = bv0.z; Bs[sk + 3][sm] = bv0.w;
    Bs[sk + 4][sm] = bv1.x; Bs[sk + 5][sm] = bv1.y;
    Bs[sk + 6][sm] = bv1.z; Bs[sk + 7][sm] = bv1.w;
    __syncthreads();
#pragma unroll
    for (int k = 0; k < BK_; ++k) {
      float a_[8], b_[8];
      *(float4*)&a_[0] = *(const float4*)&As[k][ty * 8];
      *(float4*)&a_[4] = *(const float4*)&As[k][ty * 8 + 4];
      *(float4*)&b_[0] = *(const float4*)&Bs[k][tx * 8];
      *(float4*)&b_[4] = *(const float4*)&Bs[k][tx * 8 + 4];
#pragma unroll
      for (int i = 0; i < 8; ++i)
#pragma unroll
        for (int j = 0; j < 8; ++j) acc[i][j] += a_[i] * b_[j];
    }
  }

#pragma unroll
  for (int i = 0; i < 8; ++i) {
    const size_t m = (size_t)(m0 + ty * 8 + i);
#pragma unroll
    for (int j = 0; j < 8; j += 4) {
      float4 v;
      v.x = acc[i][j + 0] + bj[j0 + tx * 8 + j + 0];
      v.y = acc[i][j + 1] + bj[j0 + tx * 8 + j + 1];
      v.z = acc[i][j + 2] + bj[j0 + tx * 8 + j + 2];
      v.w = acc[i][j + 3] + bj[j0 + tx * 8 + j + 3];
      *(float4*)(C + m * J_ + j0 + tx * 8 + j) = v;
    }
  }
}

// ============================================================
// Kernel 2: init flags + res fill
// ============================================================
__global__ void init_kernel(int* __restrict__ res) {
  const int idx = blockIdx.x * blockDim.x + threadIdx.x;
  if (idx < N_) g_flag[idx] = 0u;
  const int stride = gridDim.x * blockDim.x;
  for (size_t i = idx; i < (size_t)N_ * RESW_; i += stride) res[i] = -1;
}

// ============================================================
// Kernel 3: Xi0 table + b1s (summation order = round-1 sequential float4)
// ============================================================
__global__ __launch_bounds__(256) void xi0_kernel(
    const float* __restrict__ emb, const float* __restrict__ wi0,
    const float* __restrict__ bi0, const float* __restrict__ bh0,
    const float* __restrict__ bi1, const float* __restrict__ bh1) {
  __shared__ __align__(16) float xs[H_];
  const int s = blockIdx.x;   // 0..28 (28 = null / last<0)
  const int tid = threadIdx.x;
  for (int i = tid; i < H_; i += 256)
    xs[i] = (s < V_ - 1) ? emb[(size_t)s * H_ + i] : 0.f;
  __syncthreads();
  for (int o = tid; o < 4 * H_; o += 256) {
    float acc = bi0[o] + bh0[o];
    if (s < V_ - 1) {
      const float* wr = wi0 + (size_t)o * H_;
      for (int k = 0; k < H_; k += 4) {
        float4 x4 = *(const float4*)&xs[k];
        float4 w4 = *(const float4*)&wr[k];
        acc += x4.x * w4.x + x4.y * w4.y + x4.z * w4.z + x4.w * w4.w;
      }
    }
    g_Xi0[s][o] = acc;
    if (s == 0) g_b1s[o] = bi1[o] + bh1[o];
  }
}

// ============================================================
// Kernel 4: decode, 4 blocks/row, 2 sync rounds/emit
// ============================================================
__device__ __forceinline__ float sigmoidf_(float x) {
  return 1.f / (1.f + expf(-x));
}

__device__ __forceinline__ void flag_round(int row, int tid, int& target) {
  target += 4;
  __syncthreads();  // all exchange stores issued before flag
  if (tid == 0) {
    __hip_atomic_fetch_add(&g_flag[row], 1u, __ATOMIC_RELEASE,
                           __HIP_MEMORY_SCOPE_AGENT);
    while (__hip_atomic_load(&g_flag[row], __ATOMIC_ACQUIRE,
                             __HIP_MEMORY_SCOPE_AGENT) < (unsigned)target)
      __builtin_amdgcn_s_sleep(2);
  }
  __syncthreads();
}

// Recompute pending LSTM state + gproj from symbol s (28 = null).
// 2 flag rounds. c-state is block-local (registers of threads 0..79).
__device__ void recompute(
    int s, int row, int k, int tid, int par, int& target,
    const float* __restrict__ wh0, const float* __restrict__ wi1,
    const float* __restrict__ wh1, const float* __restrict__ w_g,
    float* h0s, float* h1s, float* gates,
    float& c0_reg, float& c1_reg, float& gp_reg) {
  const int g = tid / HS_;          // valid for tid < 320
  const int i = tid - g * HS_;
  const int o = g * H_ + k * HS_ + i;

  // ---- layer 0 gates: Xi0[s][o] + wh0[o,:] @ h0_old(full) ----
  if (tid < 4 * HS_) {
    const float* wr = wh0 + (size_t)o * H_;
    float acc = g_Xi0[s][o];
    for (int kk = 0; kk < H_; kk += 4) {
      float4 h4 = *(const float4*)&h0s[kk];
      float4 w4 = *(const float4*)&wr[kk];
      acc += h4.x * w4.x + h4.y * w4.y + h4.z * w4.z + h4.w * w4.w;
    }
    gates[tid] = acc;
  }
  __syncthreads();
  // ---- act0 -> h0 slice to exchange ----
  if (tid < HS_) {
    float ig = sigmoidf_(gates[tid]);
    float fg = sigmoidf_(gates[HS_ + tid]);
    float gg = tanhf(gates[2 * HS_ + tid]);
    float og = sigmoidf_(gates[3 * HS_ + tid]);
    float c2 = fg * c0_reg + ig * gg;
    c0_reg = c2;
    float h2 = og * tanhf(c2);
    __hip_atomic_store(&g_h0x[par][row][k * HS_ + tid], h2, __ATOMIC_RELAXED,
                       __HIP_MEMORY_SCOPE_AGENT);
  }
  // ---- overlap with S1: layer1 partial = b1s + wh1[o,:] @ h1_old(full) ----
  float acc1 = 0.f;
  if (tid < 4 * HS_) {
    const float* whr = wh1 + (size_t)o * H_;
    acc1 = g_b1s[o];
    for (int kk = 0; kk < H_; kk += 4) {
      float4 h4 = *(const float4*)&h1s[kk];
      float4 w4 = *(const float4*)&whr[kk];
      acc1 += h4.x * w4.x + h4.y * w4.y + h4.z * w4.z + h4.w * w4.w;
    }
  }
  flag_round(row, tid, target);   // S1: h0 slices ready
  if (tid < H_)
    h0s[tid] = __hip_atomic_load(&g_h0x[par][row][tid], __ATOMIC_RELAXED,
                                 __HIP_MEMORY_SCOPE_AGENT);
  __syncthreads();
  // ---- layer1 gates += wi1[o,:] @ h0_new(full) ----
  if (tid < 4 * HS_) {
    const float* wir = wi1 + (size_t)o * H_;
    for (int kk = 0; kk < H_; kk += 4) {
      float4 x4 = *(const float4*)&h0s[kk];
      float4 w4 = *(const float4*)&wir[kk];
      acc1 += x4.x * w4.x + x4.y * w4.y + x4.z * w4.z + x4.w * w4.w;
    }
    gates[tid] = acc1;
  }
  __syncthreads();
  // ---- act1 -> h1 slice (local LDS + exchange) ----
  if (tid < HS_) {
    float ig = sigmoidf_(gates[tid]);
    float fg = sigmoidf_(gates[HS_ + tid]);
    float gg = tanhf(gates[2 * HS_ + tid]);
    float og = sigmoidf_(gates[3 * HS_ + tid]);
    float c2 = fg * c1_reg + ig * gg;
    c1_reg = c2;
    float h2 = og * tanhf(c2);
    h1s[k * HS_ + tid] = h2;
    __hip_atomic_store(&g_h1x[par][row][k * HS_ + tid], h2, __ATOMIC_RELAXED,
                       __HIP_MEMORY_SCOPE_AGENT);
  }
  __syncthreads();
  // ---- gproj partial over own h1 slice: j = tid (all 512 threads) ----
  {
    const float* wgr = w_g + (size_t)tid * H_ + k * HS_;
    const float* hsl = &h1s[k * HS_];
    float a = 0.f;
    for (int kk = 0; kk < HS_; kk += 4) {
      float4 h4 = *(const float4*)&hsl[kk];
      float4 w4 = *(const float4*)&wgr[kk];
      a += h4.x * w4.x + h4.y * w4.y + h4.z * w4.z + h4.w * w4.w;
    }
    __hip_atomic_store(&g_gpx[par][row][k][tid], a, __ATOMIC_RELAXED,
                       __HIP_MEMORY_SCOPE_AGENT);
  }
  flag_round(row, tid, target);   // S2: h1 slices + gp partials ready
  {
    float a0 = __hip_atomic_load(&g_gpx[par][row][0][tid], __ATOMIC_RELAXED,
                                 __HIP_MEMORY_SCOPE_AGENT);
    float a1 = __hip_atomic_load(&g_gpx[par][row][1][tid], __ATOMIC_RELAXED,
                                 __HIP_MEMORY_SCOPE_AGENT);
    float a2 = __hip_atomic_load(&g_gpx[par][row][2][tid], __ATOMIC_RELAXED,
                                 __HIP_MEMORY_SCOPE_AGENT);
    float a3 = __hip_atomic_load(&g_gpx[par][row][3][tid], __ATOMIC_RELAXED,
                                 __HIP_MEMORY_SCOPE_AGENT);
    gp_reg = ((a0 + a1) + a2) + a3;
  }
  if (tid < H_)
    h1s[tid] = __hip_atomic_load(&g_h1x[par][row][tid], __ATOMIC_RELAXED,
                                 __HIP_MEMORY_SCOPE_AGENT);
  __syncthreads();
}

__global__ __launch_bounds__(512) void decode2(
    const float* __restrict__ Fproj, const int* __restrict__ f_lens,
    const float* __restrict__ wh0,
    const float* __restrict__ wi1, const float* __restrict__ wh1,
    const float* __restrict__ w_g,
    const float* __restrict__ w_o, const float* __restrict__ b_o,
    int* __restrict__ res, int* __restrict__ nsym) {
  const int bid = blockIdx.x;
  const int row = bid >> 2;
  const int k = bid & 3;
  const int tid = threadIdx.x;
  const int f_len = f_lens[row];

  __shared__ __align__(16) float h0s[H_], h1s[H_];
  __shared__ __align__(16) float gates[4 * HS_];
  __shared__ __align__(16) float hjs[J_];
  __shared__ float logits[32];

  // w_o in registers: thread (grp, ti) owns w_o[grp][ti + 16k]
  const int grp = tid >> 4;
  const int ti = tid & 15;
  float wo_reg[32];
  float bo_reg = 0.f;
  if (grp < V_) {
#pragma unroll
    for (int kk = 0; kk < 32; ++kk)
      wo_reg[kk] = w_o[(size_t)grp * J_ + ti + 16 * kk];
    bo_reg = b_o[grp];
  }

  for (int idx = tid; idx < H_; idx += 512) { h0s[idx] = 0.f; h1s[idx] = 0.f; }
  float c0_reg = 0.f, c1_reg = 0.f;
  float gp_reg = 0.f;
  int target = 0;
  __syncthreads();

  // initial pending state from (last=-1, h=0, c=0); Xi0 row 28 = zero input
  recompute(BLANK_, row, k, tid, 0, target, wh0, wi1, wh1, w_g,
            h0s, h1s, gates, c0_reg, c1_reg, gp_reg);
  int ecount = 1;

  // redundant per-thread decode state (bitwise-identical across threads/blocks)
  int t_loc = 0, sym_add = 0, res_idx = -1;
  float fp_cur = Fproj[(size_t)row * J_ + tid];  // t=0 row

  while (t_loc < f_len) {
    const int tnext = (t_loc + 1 < T_) ? t_loc + 1 : T_ - 1;
    float fp_next = Fproj[((size_t)tnext * N_ + row) * J_ + tid];

    float hj = fp_cur + gp_reg;
    hjs[tid] = hj > 0.f ? hj : 0.f;
    __syncthreads();                       // B1

    float p = 0.f;
    if (grp < V_) {
#pragma unroll
      for (int kk = 0; kk < 32; ++kk) p += hjs[ti + 16 * kk] * wo_reg[kk];
    }
#pragma unroll
    for (int sft = 8; sft; sft >>= 1) p += __shfl_xor(p, sft, 16);
    if (grp < V_ && ti == 0) logits[grp] = p + bo_reg;
    __syncthreads();                       // B2

    // redundant argmax (first-max tie-break, identical everywhere)
    float best = logits[0];
    int bi = 0;
#pragma unroll
    for (int v = 1; v < V_; ++v) {
      float lv = logits[v];
      if (lv > best) { best = lv; bi = v; }
    }
    const int emit = (bi != BLANK_) && (sym_add < MAXSYM_);

    if (emit) {
      res_idx += 1;
      if (k == 0 && tid == 0) res[(size_t)row * RESW_ + res_idx] = bi;
      sym_add += 1;
      recompute(bi, row, k, tid, ecount & 1, target, wh0, wi1, wh1, w_g,
                h0s, h1s, gates, c0_reg, c1_reg, gp_reg);
      ecount += 1;
    } else {
      sym_add = 0;
      t_loc += 1;
      fp_cur = fp_next;
    }
  }

  if (k == 0 && tid == 0) nsym[row] = res_idx + 1;
}

// ============================================================
extern "C" void kernel_launch(void* const* d_in, const int* in_sizes, int n_in,
                              void* d_out, int out_size, void* d_ws, size_t ws_size,
                              hipStream_t stream) {
  const float* f      = (const float*)d_in[0];
  const int*   f_lens = (const int*)d_in[1];
  const float* emb    = (const float*)d_in[2];
  const float* wi0    = (const float*)d_in[3];
  const float* wh0    = (const float*)d_in[4];
  const float* bi0    = (const float*)d_in[5];
  const float* bh0    = (const float*)d_in[6];
  const float* wi1    = (const float*)d_in[7];
  const float* wh1    = (const float*)d_in[8];
  const float* bi1    = (const float*)d_in[9];
  const float* bh1    = (const float*)d_in[10];
  const float* w_f    = (const float*)d_in[11];
  const float* w_g    = (const float*)d_in[12];
  const float* b_j    = (const float*)d_in[13];
  const float* w_o    = (const float*)d_in[14];
  const float* b_o    = (const float*)d_in[15];

  int* out  = (int*)d_out;
  int* res  = out;                       // (64, 15360)
  int* nsym = out + (size_t)N_ * RESW_;  // (64,)

  float* Fproj = (float*)d_ws;  // T*N*J*4 = 64 MiB

  init_kernel<<<1024, 256, 0, stream>>>(res);
  xi0_kernel<<<V_, 256, 0, stream>>>(emb, wi0, bi0, bh0, bi1, bh1);

  dim3 ggrid(T_ * N_ / BM_, J_ / BN_);  // (256, 4)
  fproj_gemm<<<ggrid, 256, 0, stream>>>(f, w_f, b_j, Fproj);

  decode2<<<N_ * 4, 512, 0, stream>>>(Fproj, f_lens, wh0, wi1, wh1, w_g,
                                      w_o, b_o, res, nsym);
}

// Round 4
// 1995.580 us; speedup vs baseline: 4.3963x; 1.1698x over previous
//
#include <hip/hip_runtime.h>
#include <math.h>

#define T_ 512
#define N_ 64
#define E_ 1024
#define H_ 320
#define HS8_ 40           // H_/8 per-block h-slice
#define J_ 512
#define V_ 29
#define BLANK_ 28
#define MAXSYM_ 30
#define RESW_ (MAXSYM_ * T_)   // 15360

// ---------------- static device memory ----------------
__device__ float g_Xi0[V_][4 * H_];      // wi0@emb[s]+bi0+bh0; row 28 = bias only
__device__ float g_b1s[4 * H_];          // bi1 + bh1
__device__ float g_h0x[2][N_][H_];       // exchange buffers (parity double-buffered)
__device__ float g_h1x[2][N_][H_];
__device__ float g_gpx[2][N_][8][J_];    // gproj partials per source block
__device__ unsigned int g_flag[N_];      // monotonic per-row sync counter

// ============================================================
// Kernel 1: Fproj[(t*N+n), j] = f[t,n,:] @ w_f[j,:] + b_j[j]
// ============================================================
#define BM_ 128
#define BN_ 128
#define BK_ 16

__global__ __launch_bounds__(256) void fproj_gemm(
    const float* __restrict__ A, const float* __restrict__ B,
    const float* __restrict__ bj, float* __restrict__ C) {
  __shared__ __align__(16) float As[BK_][BM_ + 4];
  __shared__ __align__(16) float Bs[BK_][BN_ + 4];
  const int tid = threadIdx.x;
  const int m0 = blockIdx.x * BM_;
  const int j0 = blockIdx.y * BN_;
  const int tx = tid & 15, ty = tid >> 4;
  const int sm = tid >> 1;
  const int sk = (tid & 1) << 3;

  float acc[8][8];
#pragma unroll
  for (int i = 0; i < 8; ++i)
#pragma unroll
    for (int j = 0; j < 8; ++j) acc[i][j] = 0.f;

  for (int kc = 0; kc < E_; kc += BK_) {
    float4 av0 = *(const float4*)(A + (size_t)(m0 + sm) * E_ + kc + sk);
    float4 av1 = *(const float4*)(A + (size_t)(m0 + sm) * E_ + kc + sk + 4);
    float4 bv0 = *(const float4*)(B + (size_t)(j0 + sm) * E_ + kc + sk);
    float4 bv1 = *(const float4*)(B + (size_t)(j0 + sm) * E_ + kc + sk + 4);
    __syncthreads();
    As[sk + 0][sm] = av0.x; As[sk + 1][sm] = av0.y;
    As[sk + 2][sm] = av0.z; As[sk + 3][sm] = av0.w;
    As[sk + 4][sm] = av1.x; As[sk + 5][sm] = av1.y;
    As[sk + 6][sm] = av1.z; As[sk + 7][sm] = av1.w;
    Bs[sk + 0][sm] = bv0.x; Bs[sk + 1][sm] = bv0.y;
    Bs[sk + 2][sm] = bv0.z; Bs[sk + 3][sm] = bv0.w;
    Bs[sk + 4][sm] = bv1.x; Bs[sk + 5][sm] = bv1.y;
    Bs[sk + 6][sm] = bv1.z; Bs[sk + 7][sm] = bv1.w;
    __syncthreads();
#pragma unroll
    for (int k = 0; k < BK_; ++k) {
      float a_[8], b_[8];
      *(float4*)&a_[0] = *(const float4*)&As[k][ty * 8];
      *(float4*)&a_[4] = *(const float4*)&As[k][ty * 8 + 4];
      *(float4*)&b_[0] = *(const float4*)&Bs[k][tx * 8];
      *(float4*)&b_[4] = *(const float4*)&Bs[k][tx * 8 + 4];
#pragma unroll
      for (int i = 0; i < 8; ++i)
#pragma unroll
        for (int j = 0; j < 8; ++j) acc[i][j] += a_[i] * b_[j];
    }
  }

#pragma unroll
  for (int i = 0; i < 8; ++i) {
    const size_t m = (size_t)(m0 + ty * 8 + i);
#pragma unroll
    for (int j = 0; j < 8; j += 4) {
      float4 v;
      v.x = acc[i][j + 0] + bj[j0 + tx * 8 + j + 0];
      v.y = acc[i][j + 1] + bj[j0 + tx * 8 + j + 1];
      v.z = acc[i][j + 2] + bj[j0 + tx * 8 + j + 2];
      v.w = acc[i][j + 3] + bj[j0 + tx * 8 + j + 3];
      *(float4*)(C + m * J_ + j0 + tx * 8 + j) = v;
    }
  }
}

// ============================================================
// Kernel 2: init flags + res fill
// ============================================================
__global__ void init_kernel(int* __restrict__ res) {
  const int idx = blockIdx.x * blockDim.x + threadIdx.x;
  if (idx < N_) g_flag[idx] = 0u;
  const int stride = gridDim.x * blockDim.x;
  for (size_t i = idx; i < (size_t)N_ * RESW_; i += stride) res[i] = -1;
}

// ============================================================
// Kernel 3: Xi0 table + b1s (summation order = sequential float4)
// ============================================================
__global__ __launch_bounds__(256) void xi0_kernel(
    const float* __restrict__ emb, const float* __restrict__ wi0,
    const float* __restrict__ bi0, const float* __restrict__ bh0,
    const float* __restrict__ bi1, const float* __restrict__ bh1) {
  __shared__ __align__(16) float xs[H_];
  const int s = blockIdx.x;   // 0..28 (28 = null / last<0)
  const int tid = threadIdx.x;
  for (int i = tid; i < H_; i += 256)
    xs[i] = (s < V_ - 1) ? emb[(size_t)s * H_ + i] : 0.f;
  __syncthreads();
  for (int o = tid; o < 4 * H_; o += 256) {
    float acc = bi0[o] + bh0[o];
    if (s < V_ - 1) {
      const float* wr = wi0 + (size_t)o * H_;
      for (int k = 0; k < H_; k += 4) {
        float4 x4 = *(const float4*)&xs[k];
        float4 w4 = *(const float4*)&wr[k];
        acc += x4.x * w4.x + x4.y * w4.y + x4.z * w4.z + x4.w * w4.w;
      }
    }
    g_Xi0[s][o] = acc;
    if (s == 0) g_b1s[o] = bi1[o] + bh1[o];
  }
}

// ============================================================
// Kernel 4: decode, 8 blocks/row x 256 threads (512 blocks, 2/CU)
// ============================================================
__device__ __forceinline__ float sigmoidf_(float x) {
  return 1.f / (1.f + expf(-x));
}

__device__ __forceinline__ void flag_round8(int row, int tid, int& target) {
  target += 8;
  __syncthreads();  // all exchange stores issued/drained before flag
  if (tid == 0) {
    __hip_atomic_fetch_add(&g_flag[row], 1u, __ATOMIC_RELEASE,
                           __HIP_MEMORY_SCOPE_AGENT);
    while (__hip_atomic_load(&g_flag[row], __ATOMIC_ACQUIRE,
                             __HIP_MEMORY_SCOPE_AGENT) < (unsigned)target)
      __builtin_amdgcn_s_sleep(2);
  }
  __syncthreads();
}

// Recompute pending LSTM state + gproj from symbol s (28 = null).
// 2 flag rounds. c-state block-local (registers of threads 0..39).
__device__ void recompute8(
    int s, int row, int k8, int tid, int par, int& target,
    const float* __restrict__ wh0, const float* __restrict__ wi1,
    const float* __restrict__ wh1, const float* __restrict__ w_g,
    float* h0s, float* h1s, float* gates,
    float& c0, float& c1, float2& gp) {
  const int g = tid / HS8_;           // valid for tid < 160
  const int il = tid - g * HS8_;
  const int o = g * H_ + k8 * HS8_ + il;

  // ---- layer 0 gates: Xi0[s][o] + wh0[o,:] @ h0_old(full) ----
  if (tid < 4 * HS8_) {
    const float* wr = wh0 + (size_t)o * H_;
    float acc = g_Xi0[s][o];
    for (int kk = 0; kk < H_; kk += 4) {
      float4 h4 = *(const float4*)&h0s[kk];
      float4 w4 = *(const float4*)&wr[kk];
      acc += h4.x * w4.x + h4.y * w4.y + h4.z * w4.z + h4.w * w4.w;
    }
    gates[tid] = acc;
  }
  __syncthreads();
  if (tid < HS8_) {
    float ig = sigmoidf_(gates[tid]);
    float fg = sigmoidf_(gates[HS8_ + tid]);
    float gg = tanhf(gates[2 * HS8_ + tid]);
    float og = sigmoidf_(gates[3 * HS8_ + tid]);
    float c2 = fg * c0 + ig * gg;
    c0 = c2;
    float h2 = og * tanhf(c2);
    __hip_atomic_store(&g_h0x[par][row][k8 * HS8_ + tid], h2, __ATOMIC_RELAXED,
                       __HIP_MEMORY_SCOPE_AGENT);
  }
  // ---- overlap S1 wait with wh1 @ h1_old ----
  float acc1 = 0.f;
  if (tid < 4 * HS8_) {
    const float* whr = wh1 + (size_t)o * H_;
    acc1 = g_b1s[o];
    for (int kk = 0; kk < H_; kk += 4) {
      float4 h4 = *(const float4*)&h1s[kk];
      float4 w4 = *(const float4*)&whr[kk];
      acc1 += h4.x * w4.x + h4.y * w4.y + h4.z * w4.z + h4.w * w4.w;
    }
  }
  flag_round8(row, tid, target);   // S1: h0 slices ready
  h0s[tid] = __hip_atomic_load(&g_h0x[par][row][tid], __ATOMIC_RELAXED,
                               __HIP_MEMORY_SCOPE_AGENT);
  if (tid < H_ - 256)
    h0s[256 + tid] = __hip_atomic_load(&g_h0x[par][row][256 + tid],
                                       __ATOMIC_RELAXED, __HIP_MEMORY_SCOPE_AGENT);
  __syncthreads();
  // ---- layer1 gates += wi1[o,:] @ h0_new(full) ----
  if (tid < 4 * HS8_) {
    const float* wir = wi1 + (size_t)o * H_;
    for (int kk = 0; kk < H_; kk += 4) {
      float4 x4 = *(const float4*)&h0s[kk];
      float4 w4 = *(const float4*)&wir[kk];
      acc1 += x4.x * w4.x + x4.y * w4.y + x4.z * w4.z + x4.w * w4.w;
    }
    gates[tid] = acc1;
  }
  __syncthreads();
  if (tid < HS8_) {
    float ig = sigmoidf_(gates[tid]);
    float fg = sigmoidf_(gates[HS8_ + tid]);
    float gg = tanhf(gates[2 * HS8_ + tid]);
    float og = sigmoidf_(gates[3 * HS8_ + tid]);
    float c2 = fg * c1 + ig * gg;
    c1 = c2;
    float h2 = og * tanhf(c2);
    h1s[k8 * HS8_ + tid] = h2;
    __hip_atomic_store(&g_h1x[par][row][k8 * HS8_ + tid], h2, __ATOMIC_RELAXED,
                       __HIP_MEMORY_SCOPE_AGENT);
  }
  __syncthreads();
  // ---- gproj partials over own h1 slice: j = tid, tid+256 ----
  {
    const float* hsl = &h1s[k8 * HS8_];
#pragma unroll
    for (int jj = 0; jj < 2; ++jj) {
      const int j = tid + jj * 256;
      const float* wgr = w_g + (size_t)j * H_ + k8 * HS8_;
      float a = 0.f;
      for (int kk = 0; kk < HS8_; kk += 4) {
        float4 h4 = *(const float4*)&hsl[kk];
        float4 w4 = *(const float4*)&wgr[kk];
        a += h4.x * w4.x + h4.y * w4.y + h4.z * w4.z + h4.w * w4.w;
      }
      __hip_atomic_store(&g_gpx[par][row][k8][j], a, __ATOMIC_RELAXED,
                         __HIP_MEMORY_SCOPE_AGENT);
    }
  }
  flag_round8(row, tid, target);   // S2: h1 slices + gp partials ready
  {
    float ax = 0.f, ay = 0.f;
#pragma unroll
    for (int kk = 0; kk < 8; ++kk) {
      ax += __hip_atomic_load(&g_gpx[par][row][kk][2 * tid], __ATOMIC_RELAXED,
                              __HIP_MEMORY_SCOPE_AGENT);
      ay += __hip_atomic_load(&g_gpx[par][row][kk][2 * tid + 1], __ATOMIC_RELAXED,
                              __HIP_MEMORY_SCOPE_AGENT);
    }
    gp.x = ax; gp.y = ay;
  }
  h1s[tid] = __hip_atomic_load(&g_h1x[par][row][tid], __ATOMIC_RELAXED,
                               __HIP_MEMORY_SCOPE_AGENT);
  if (tid < H_ - 256)
    h1s[256 + tid] = __hip_atomic_load(&g_h1x[par][row][256 + tid],
                                       __ATOMIC_RELAXED, __HIP_MEMORY_SCOPE_AGENT);
  __syncthreads();
}

__global__ __launch_bounds__(256, 2) void decode8(
    const float* __restrict__ Fproj, const int* __restrict__ f_lens,
    const float* __restrict__ wh0,
    const float* __restrict__ wi1, const float* __restrict__ wh1,
    const float* __restrict__ w_g,
    const float* __restrict__ w_o, const float* __restrict__ b_o,
    int* __restrict__ res, int* __restrict__ nsym) {
  const int bid = blockIdx.x;
  const int k8 = bid & 7;                       // slice -> XCD (bid%8)
  const int row = ((bid >> 3) + 8 * k8) & 63;   // anti-aligned co-residency
  const int tid = threadIdx.x;
  const int f_len = f_lens[row];

  __shared__ __align__(16) float h0s[H_], h1s[H_];
  __shared__ __align__(16) float gates[4 * HS8_];
  __shared__ __align__(16) float hjs[J_];
  __shared__ float logits[32];

  // blank-path: v = tid>>3 (vocab word), lq = tid&7; lane covers
  // j = lq*4 + 32*q + e (q<16, e<4) -> 16 float4, bank-spread
  const int v = tid >> 3;
  const int lq = tid & 7;
  float4 wo[16];
  float bo = 0.f;
  if (v < V_) {
#pragma unroll
    for (int q = 0; q < 16; ++q)
      wo[q] = *(const float4*)(w_o + (size_t)v * J_ + lq * 4 + 32 * q);
    bo = b_o[v];
  }

  for (int i = tid; i < H_; i += 256) { h0s[i] = 0.f; h1s[i] = 0.f; }
  float c0 = 0.f, c1 = 0.f;
  float2 gp = {0.f, 0.f};
  int target = 0;
  __syncthreads();

  // initial pending state from (last=-1, h=0, c=0)
  recompute8(BLANK_, row, k8, tid, 0, target, wh0, wi1, wh1, w_g,
             h0s, h1s, gates, c0, c1, gp);
  int ecount = 1;

  int t_loc = 0, sym_add = 0, res_idx = -1;
  float2 fp = *(const float2*)(Fproj + (size_t)row * J_ + 2 * tid);  // t=0

  while (t_loc < f_len) {
    const int tn = (t_loc + 1 < T_) ? t_loc + 1 : T_ - 1;
    float2 fpn = *(const float2*)(Fproj + ((size_t)tn * N_ + row) * J_ + 2 * tid);

    float hx = fp.x + gp.x, hy = fp.y + gp.y;
    float2 hj2 = {hx > 0.f ? hx : 0.f, hy > 0.f ? hy : 0.f};
    *(float2*)&hjs[2 * tid] = hj2;
    __syncthreads();                    // B1

    float p = 0.f;
    if (v < V_) {
#pragma unroll
      for (int q = 0; q < 16; ++q) {
        float4 h4 = *(const float4*)&hjs[lq * 4 + 32 * q];
        p += h4.x * wo[q].x + h4.y * wo[q].y + h4.z * wo[q].z + h4.w * wo[q].w;
      }
    }
    p += __shfl_xor(p, 4, 8);
    p += __shfl_xor(p, 2, 8);
    p += __shfl_xor(p, 1, 8);
    if (v < V_ && lq == 0) logits[v] = p + bo;
    __syncthreads();                    // B2

    // redundant argmax (first-max tie-break, identical everywhere)
    float best = logits[0];
    int bi = 0;
#pragma unroll
    for (int vv = 1; vv < V_; ++vv) {
      float lv = logits[vv];
      if (lv > best) { best = lv; bi = vv; }
    }
    const int emit = (bi != BLANK_) && (sym_add < MAXSYM_);

    if (emit) {
      res_idx += 1;
      if (k8 == 0 && tid == 0) res[(size_t)row * RESW_ + res_idx] = bi;
      sym_add += 1;
      recompute8(bi, row, k8, tid, ecount & 1, target, wh0, wi1, wh1, w_g,
                 h0s, h1s, gates, c0, c1, gp);
      ecount += 1;
    } else {
      sym_add = 0;
      t_loc += 1;
      fp = fpn;
    }
  }

  if (k8 == 0 && tid == 0) nsym[row] = res_idx + 1;
}

// ============================================================
extern "C" void kernel_launch(void* const* d_in, const int* in_sizes, int n_in,
                              void* d_out, int out_size, void* d_ws, size_t ws_size,
                              hipStream_t stream) {
  const float* f      = (const float*)d_in[0];
  const int*   f_lens = (const int*)d_in[1];
  const float* emb    = (const float*)d_in[2];
  const float* wi0    = (const float*)d_in[3];
  const float* wh0    = (const float*)d_in[4];
  const float* bi0    = (const float*)d_in[5];
  const float* bh0    = (const float*)d_in[6];
  const float* wi1    = (const float*)d_in[7];
  const float* wh1    = (const float*)d_in[8];
  const float* bi1    = (const float*)d_in[9];
  const float* bh1    = (const float*)d_in[10];
  const float* w_f    = (const float*)d_in[11];
  const float* w_g    = (const float*)d_in[12];
  const float* b_j    = (const float*)d_in[13];
  const float* w_o    = (const float*)d_in[14];
  const float* b_o    = (const float*)d_in[15];

  int* out  = (int*)d_out;
  int* res  = out;                       // (64, 15360)
  int* nsym = out + (size_t)N_ * RESW_;  // (64,)

  float* Fproj = (float*)d_ws;  // T*N*J*4 = 64 MiB

  init_kernel<<<1024, 256, 0, stream>>>(res);
  xi0_kernel<<<V_, 256, 0, stream>>>(emb, wi0, bi0, bh0, bi1, bh1);

  dim3 ggrid(T_ * N_ / BM_, J_ / BN_);  // (256, 4)
  fproj_gemm<<<ggrid, 256, 0, stream>>>(f, w_f, b_j, Fproj);

  decode8<<<N_ * 8, 256, 0, stream>>>(Fproj, f_lens, wh0, wi1, wh1, w_g,
                                      w_o, b_o, res, nsym);
}